// Round 16
// baseline (382.102 us; speedup 1.0000x reference)
//
#include <hip/hip_runtime.h>
#include <hip/hip_bf16.h>
#include <stdint.h>

#define DIM   1024
#define ODIM  3072
#define MROWS 32768   // B(8) * N(4096)
#define RANK  8

typedef unsigned short u16;
typedef __attribute__((ext_vector_type(8))) short short8;
typedef __attribute__((ext_vector_type(8))) unsigned short u16x8;
typedef __attribute__((ext_vector_type(4))) unsigned short u16x4;
typedef __attribute__((ext_vector_type(4))) float f32x4;

__device__ __forceinline__ u16 f2bf(float f) {
    uint32_t u = __float_as_uint(f);
    u += 0x7fffu + ((u >> 16) & 1u);   // RNE
    return (u16)(u >> 16);
}

__device__ __forceinline__ void gl2lds16(const void* g, void* l) {
    __builtin_amdgcn_global_load_lds(
        (const __attribute__((address_space(1))) void*)(uintptr_t)g,
        (__attribute__((address_space(3))) void*)(uint32_t)(uintptr_t)l,
        16, 0, 0);
}

#define BAR()    do { asm volatile("" ::: "memory"); __builtin_amdgcn_s_barrier(); asm volatile("" ::: "memory"); } while (0)
#define WAITV0() asm volatile("s_waitcnt vmcnt(0)" ::: "memory")
#define WAITL0() asm volatile("s_waitcnt lgkmcnt(0)" ::: "memory")
#define SCHED0() __builtin_amdgcn_sched_barrier(0)

// ---------------- fused prep: convert X | convert Wk | build Wmq/Wmv ----------------
__device__ __forceinline__ u16x8 cvt8_nt(const float* __restrict__ src) {
    f32x4 a = __builtin_nontemporal_load(reinterpret_cast<const f32x4*>(src));
    f32x4 b = __builtin_nontemporal_load(reinterpret_cast<const f32x4*>(src) + 1);
    u16x8 o;
    o[0] = f2bf(a[0]); o[1] = f2bf(a[1]); o[2] = f2bf(a[2]); o[3] = f2bf(a[3]);
    o[4] = f2bf(b[0]); o[5] = f2bf(b[1]); o[6] = f2bf(b[2]); o[7] = f2bf(b[3]);
    return o;
}

__global__ __launch_bounds__(256) void k_prep(const float* __restrict__ x,
                                              const float* __restrict__ W,
                                              const float* __restrict__ Aq_pool,
                                              const float* __restrict__ Bq_pool,
                                              const float* __restrict__ Av_pool,
                                              const float* __restrict__ Bv_pool,
                                              const int* __restrict__ idx,
                                              u16* __restrict__ Xc,
                                              u16* __restrict__ Wk,
                                              u16* __restrict__ Wmq,
                                              u16* __restrict__ Wmv) {
    if (blockIdx.x < 2048) {                       // ---- X convert ----
        const int stride = 2048 * 256;
        for (int t = blockIdx.x * 256 + threadIdx.x; t * 8 < MROWS * DIM; t += stride) {
            const int i = t * 8;
            *reinterpret_cast<u16x8*>(Xc + i) = cvt8_nt(x + i);
        }
        return;
    }
    if (blockIdx.x < 2560) {                       // ---- Wk convert ----
        const int i = ((blockIdx.x - 2048) * 256 + threadIdx.x) * 8;
        *reinterpret_cast<u16x8*>(Wk + i) = cvt8_nt(W + (size_t)DIM * DIM + i);
        return;
    }
    // ---- build ----
    const int bb = blockIdx.x - 2560;
    const int b  = bb >> 7;
    const int s  = (bb >> 6) & 1;
    const int og = bb & 63;
    const int p  = idx[b];
    const float* A  = (s ? Av_pool : Aq_pool) + (size_t)p * DIM * RANK;
    const float* Bp = (s ? Bv_pool : Bq_pool) + (size_t)p * RANK * DIM;
    const float* Ws = W + (size_t)(s ? 2048 : 0) * DIM;
    u16* dst = (s ? Wmv : Wmq) + (size_t)b * DIM * DIM;

    const int t  = threadIdx.x;
    const int i0 = t * 4;
    float a[4][8];
    #pragma unroll
    for (int ii = 0; ii < 4; ++ii) {
        float4 a0 = reinterpret_cast<const float4*>(A + (size_t)(i0 + ii) * RANK)[0];
        float4 a1 = reinterpret_cast<const float4*>(A + (size_t)(i0 + ii) * RANK)[1];
        a[ii][0] = a0.x; a[ii][1] = a0.y; a[ii][2] = a0.z; a[ii][3] = a0.w;
        a[ii][4] = a1.x; a[ii][5] = a1.y; a[ii][6] = a1.z; a[ii][7] = a1.w;
    }
    for (int r = 0; r < 16; ++r) {
        const int o = og * 16 + r;
        float bv[8];
        #pragma unroll
        for (int rr = 0; rr < 8; ++rr) bv[rr] = Bp[(size_t)rr * DIM + o];
        f32x4 w = __builtin_nontemporal_load(
            reinterpret_cast<const f32x4*>(Ws + (size_t)o * DIM + i0));
        u16x4 ov;
        #pragma unroll
        for (int ii = 0; ii < 4; ++ii) {
            float d = 0.f;
            #pragma unroll
            for (int rr = 0; rr < 8; ++rr) d += a[ii][rr] * bv[rr];
            ov[ii] = f2bf(w[ii] + d);
        }
        *reinterpret_cast<u16x4*>(dst + (size_t)o * DIM + i0) = ov;
    }
}

// ---------------- 256x256 8-wave GEMM: A via LDS, B direct global->VGPR ----------
// Motivation (R15 pipe budget): LDS was the most-loaded pipe (2816 cyc/tile vs
// MFMA 2366) and 8 barriers/tile serialized it. B-frag rows are per-(wc,lane)
// exclusive and W-panels are L2-resident (Wk shared by 128 blocks, Wm by 16) —
// so B loads straight to regs (plain C loads; compiler inserts its own vmcnt
// before first use). B frags are TIME-SHARED: reload b0 <- tile t+1 right
// after b0's last MFMA of tile t (T16), so no Bnext registers.
// LDS: A only, 2 x 256x64 bf16 = 64 KiB, proven 0-conflict layout (row r 128B,
// 16B group g at slot g^(r&7); gl2lds linear dest + pre-swizzled global src).
// Sync per tile: ONE vmcnt(0)+BAR at tile end. vmcnt(0) is count-independent
// (no fragile ledgers): in steady state everything it waits on was issued
// >= 1 tile (~2400 cyc) earlier except the trailing b1 reload (~200cyc L2).
// Buffer safety: gl2lds writes buf[(t+1)&1]; tile t reads buf[t&1]; the
// written buffer was last read before the END-of-(t-1) barrier. Race-free.

__device__ __forceinline__ void stage_half(const u16* __restrict__ mat, int row0, int tk,
                                           u16* dst, int wave, int lane) {
    const int lrow = lane >> 3;
    const int g    = (lane & 7) ^ lrow;          // pre-swizzled 16B group
    const u16* gp = mat + (size_t)(row0 + wave * 8 + lrow) * DIM + tk + g * 8;
    u16* lp = dst + wave * 8 * 64;               // wave-uniform LDS base
    gl2lds16(gp, lp);
    gl2lds16(gp + (size_t)64 * DIM, lp + 64 * 64);
}

__device__ __forceinline__ void ds_read_A(const u16* sA, int wr, int lane,
                                          int kx0, int kx1, int mh, short8 (&a)[4][2]) {
    #pragma unroll
    for (int f = 0; f < 4; ++f) {
        const int row = wr * 64 + f * 16 + mh * 128 + (lane & 15);
        a[f][0] = *reinterpret_cast<const short8*>(sA + row * 64 + kx0);
        a[f][1] = *reinterpret_cast<const short8*>(sA + row * 64 + kx1);
    }
}

// B fragment nh (2 sub-frags x 2 k-halves) straight from global (L2-hot)
__device__ __forceinline__ void load_B(const u16* __restrict__ bgl, int nh, int tk,
                                       short8 (&b)[2][2]) {
    #pragma unroll
    for (int g = 0; g < 2; ++g)
        #pragma unroll
        for (int ks = 0; ks < 2; ++ks)
            b[g][ks] = *reinterpret_cast<const short8*>(
                bgl + (size_t)((nh * 2 + g) * 64) * DIM + tk + ks * 32);
}

template <int MH, int NH>
__device__ __forceinline__ void mfma_quad(const short8 (&a)[4][2], const short8 (&b)[2][2],
                                          f32x4 (&acc)[8][4]) {
    #pragma unroll
    for (int ks = 0; ks < 2; ++ks)
        #pragma unroll
        for (int f = 0; f < 4; ++f)
            #pragma unroll
            for (int g = 0; g < 2; ++g)
                acc[MH * 4 + f][NH * 2 + g] = __builtin_amdgcn_mfma_f32_16x16x32_bf16(
                    a[f][ks], b[g][ks], acc[MH * 4 + f][NH * 2 + g], 0, 0, 0);
}

__global__ __launch_bounds__(512, 2) void k_gemm(const u16* __restrict__ Xc,
                                                 const u16* __restrict__ Wk,
                                                 const u16* __restrict__ Wmq,
                                                 const u16* __restrict__ Wmv,
                                                 const float* __restrict__ bias,
                                                 float* __restrict__ out) {
    extern __shared__ u16 lds[];               // 64 KiB: 2 x 16384 u16
    const int tid  = threadIdx.x;
    const int lane = tid & 63, wave = tid >> 6;
    const int wr = wave >> 2, wc = wave & 3;   // 2M x 4N wave grid

    // bijective XCD swizzle (nwg=1536, 1536%8==0)
    const int orig = blockIdx.x;
    const int wg   = (orig & 7) * 192 + (orig >> 3);
    const int bn   = wg % 12;
    const int bm   = wg / 12;
    const int m0 = bm * 256, n0 = bn * 256;
    const int batch = m0 >> 12;

    const u16* Bmat;
    int nc;
    if (n0 < DIM)           { Bmat = Wmq + (size_t)batch * DIM * DIM; nc = n0; }
    else if (n0 < 2 * DIM)  { Bmat = Wk;                              nc = n0 - DIM; }
    else                    { Bmat = Wmv + (size_t)batch * DIM * DIM; nc = n0 - 2 * DIM; }

    const int kx0 = (((lane >> 4)    ) ^ (lane & 7)) * 8;
    const int kx1 = (((lane >> 4) + 4) ^ (lane & 7)) * 8;

    // per-lane B base: row (nc + wc*16 + lane&15), col (lane>>4)*8
    const u16* bgl = Bmat + (size_t)(nc + wc * 16 + (lane & 15)) * DIM + (lane >> 4) * 8;

    f32x4 acc[8][4] = {};
    short8 b0[2][2], b1[2][2];

    // prologue: stage A(0) into buf0; load B(0) into regs; drain; barrier
    stage_half(Xc, m0,       0, lds,            wave, lane);
    stage_half(Xc, m0 + 128, 0, lds + 128 * 64, wave, lane);
    load_B(bgl, 0, 0, b0);
    load_B(bgl, 1, 0, b1);
    WAITV0(); BAR();

    #pragma unroll 1
    for (int t = 0; t < 15; ++t) {
        const u16* rbuf = lds + (t & 1) * 16384;
        u16* wbuf = lds + ((t + 1) & 1) * 16384;
        const int tk1 = (t + 1) * 64;
        short8 a_lo[4][2], a_hi[4][2];

        // stage A(t+1) (4 gl2lds) — retired by tile-end vmcnt(0)
        stage_half(Xc, m0,       tk1, wbuf,            wave, lane);
        stage_half(Xc, m0 + 128, tk1, wbuf + 128 * 64, wave, lane);

        // read all A frags of tile t
        ds_read_A(rbuf, wr, lane, kx0, kx1, 0, a_lo);
        ds_read_A(rbuf, wr, lane, kx0, kx1, 1, a_hi);

        // cluster 1: b0 quads (32 MFMA)
        WAITL0(); SCHED0();
        __builtin_amdgcn_s_setprio(1);
        mfma_quad<0, 0>(a_lo, b0, acc);
        mfma_quad<1, 0>(a_hi, b0, acc);
        __builtin_amdgcn_s_setprio(0);
        SCHED0();

        load_B(bgl, 0, tk1, b0);       // reload b0 <- tile t+1 (hidden under cluster 2)
        SCHED0();

        // cluster 2: b1 quads (32 MFMA)
        __builtin_amdgcn_s_setprio(1);
        mfma_quad<0, 1>(a_lo, b1, acc);
        mfma_quad<1, 1>(a_hi, b1, acc);
        __builtin_amdgcn_s_setprio(0);
        SCHED0();

        load_B(bgl, 1, tk1, b1);       // reload b1 <- tile t+1 (trailing, ~L2 latency)

        WAITV0(); BAR();               // count-independent drain: A(t+1) + B(t+1) landed
    }

    // ---- tail: tile 15, no staging/reloads ----
    {
        const u16* rbuf = lds + 16384; // 15 & 1 == 1
        short8 a_lo[4][2], a_hi[4][2];
        ds_read_A(rbuf, wr, lane, kx0, kx1, 0, a_lo);
        ds_read_A(rbuf, wr, lane, kx0, kx1, 1, a_hi);
        WAITL0(); SCHED0();
        __builtin_amdgcn_s_setprio(1);
        mfma_quad<0, 0>(a_lo, b0, acc);
        mfma_quad<1, 0>(a_hi, b0, acc);
        mfma_quad<0, 1>(a_lo, b1, acc);
        mfma_quad<1, 1>(a_hi, b1, acc);
        __builtin_amdgcn_s_setprio(0);
    }

    // ---------------- epilogue: bias + store (plain; L2 write-combining) ----------
    const int cn = wc * 16 + (lane & 15);      // col within 256-block, + ni*64
    float bcol[4];
    #pragma unroll
    for (int ni = 0; ni < 4; ++ni) bcol[ni] = bias[n0 + cn + ni * 64];
    #pragma unroll
    for (int mi = 0; mi < 8; ++mi) {
        const int rb = m0 + wr * 64 + (mi & 3) * 16 + (mi >> 2) * 128 + (lane >> 4) * 4;
        #pragma unroll
        for (int v = 0; v < 4; ++v) {
            const size_t row = (size_t)(rb + v);
            #pragma unroll
            for (int ni = 0; ni < 4; ++ni)
                out[row * ODIM + (size_t)(n0 + cn + ni * 64)] = acc[mi][ni][v] + bcol[ni];
        }
    }
}

extern "C" void kernel_launch(void* const* d_in, const int* in_sizes, int n_in,
                              void* d_out, int out_size, void* d_ws, size_t ws_size,
                              hipStream_t stream) {
    const float* x      = (const float*)d_in[0];
    const float* weight = (const float*)d_in[1];
    const float* bias   = (const float*)d_in[2];
    const float* Aq     = (const float*)d_in[3];
    const float* Bq     = (const float*)d_in[4];
    const float* Av     = (const float*)d_in[5];
    const float* Bv     = (const float*)d_in[6];
    const int*   idx    = (const int*)d_in[7];
    float* out = (float*)d_out;

    // workspace: Xc(64MB) | Wk(2MB) | Wmq(16MB) | Wmv(16MB) = 98MB
    u16* Xc  = (u16*)d_ws;
    u16* Wk  = Xc + (size_t)MROWS * DIM;
    u16* Wmq = Wk + (size_t)DIM * DIM;
    u16* Wmv = Wmq + (size_t)8 * DIM * DIM;

    hipFuncSetAttribute(reinterpret_cast<const void*>(k_gemm),
                        hipFuncAttributeMaxDynamicSharedMemorySize, 65536);

    k_prep<<<3584, 256, 0, stream>>>(x, weight, Aq, Bq, Av, Bv, idx, Xc, Wk, Wmq, Wmv);
    k_gemm<<<1536, 512, 65536, stream>>>(Xc, Wk, Wmq, Wmv, bias, out);
}

// Round 17
// 277.913 us; speedup vs baseline: 1.3749x; 1.3749x over previous
//
#include <hip/hip_runtime.h>
#include <hip/hip_bf16.h>
#include <stdint.h>

#define DIM   1024
#define ODIM  3072
#define MROWS 32768   // B(8) * N(4096)
#define RANK  8

typedef unsigned short u16;
typedef __attribute__((ext_vector_type(8))) short short8;
typedef __attribute__((ext_vector_type(8))) unsigned short u16x8;
typedef __attribute__((ext_vector_type(4))) unsigned short u16x4;
typedef __attribute__((ext_vector_type(4))) float f32x4;

__device__ __forceinline__ u16 f2bf(float f) {
    uint32_t u = __float_as_uint(f);
    u += 0x7fffu + ((u >> 16) & 1u);   // RNE
    return (u16)(u >> 16);
}

__device__ __forceinline__ void gl2lds16(const void* g, void* l) {
    __builtin_amdgcn_global_load_lds(
        (const __attribute__((address_space(1))) void*)(uintptr_t)g,
        (__attribute__((address_space(3))) void*)(uint32_t)(uintptr_t)l,
        16, 0, 0);
}

#define BAR()    do { asm volatile("" ::: "memory"); __builtin_amdgcn_s_barrier(); asm volatile("" ::: "memory"); } while (0)
#define WAITV4() asm volatile("s_waitcnt vmcnt(4)" ::: "memory")
#define WAITV2() asm volatile("s_waitcnt vmcnt(2)" ::: "memory")
#define WAITV0() asm volatile("s_waitcnt vmcnt(0)" ::: "memory")
#define WAITL0() asm volatile("s_waitcnt lgkmcnt(0)" ::: "memory")
#define WAITL8() asm volatile("s_waitcnt lgkmcnt(8)" ::: "memory")
#define SCHED0() __builtin_amdgcn_sched_barrier(0)

// ---------------- fused prep: convert X | convert Wk | build Wmq/Wmv ----------------
// blocks [0,2048): X f32->bf16 (grid-stride); [2048,2560): Wk convert;
// [2560,3584): Wmod[b] = W_slab + (A[idx_b]@B[idx_b])^T, bf16.
// Read-once f32 sources use nontemporal LOADS. NT STORES refuted (R14: +32%
// write amplification). B-direct-global in k_gemm refuted (R16: uncoalesced
// 16-row scatter, MfmaUtil 37->23%).

__device__ __forceinline__ u16x8 cvt8_nt(const float* __restrict__ src) {
    f32x4 a = __builtin_nontemporal_load(reinterpret_cast<const f32x4*>(src));
    f32x4 b = __builtin_nontemporal_load(reinterpret_cast<const f32x4*>(src) + 1);
    u16x8 o;
    o[0] = f2bf(a[0]); o[1] = f2bf(a[1]); o[2] = f2bf(a[2]); o[3] = f2bf(a[3]);
    o[4] = f2bf(b[0]); o[5] = f2bf(b[1]); o[6] = f2bf(b[2]); o[7] = f2bf(b[3]);
    return o;
}

__global__ __launch_bounds__(256) void k_prep(const float* __restrict__ x,
                                              const float* __restrict__ W,
                                              const float* __restrict__ Aq_pool,
                                              const float* __restrict__ Bq_pool,
                                              const float* __restrict__ Av_pool,
                                              const float* __restrict__ Bv_pool,
                                              const int* __restrict__ idx,
                                              u16* __restrict__ Xc,
                                              u16* __restrict__ Wk,
                                              u16* __restrict__ Wmq,
                                              u16* __restrict__ Wmv) {
    if (blockIdx.x < 2048) {                       // ---- X convert ----
        const int stride = 2048 * 256;
        for (int t = blockIdx.x * 256 + threadIdx.x; t * 8 < MROWS * DIM; t += stride) {
            const int i = t * 8;
            *reinterpret_cast<u16x8*>(Xc + i) = cvt8_nt(x + i);
        }
        return;
    }
    if (blockIdx.x < 2560) {                       // ---- Wk convert ----
        const int i = ((blockIdx.x - 2048) * 256 + threadIdx.x) * 8;
        *reinterpret_cast<u16x8*>(Wk + i) = cvt8_nt(W + (size_t)DIM * DIM + i);
        return;
    }
    // ---- build ----
    const int bb = blockIdx.x - 2560;
    const int b  = bb >> 7;
    const int s  = (bb >> 6) & 1;
    const int og = bb & 63;
    const int p  = idx[b];
    const float* A  = (s ? Av_pool : Aq_pool) + (size_t)p * DIM * RANK;
    const float* Bp = (s ? Bv_pool : Bq_pool) + (size_t)p * RANK * DIM;
    const float* Ws = W + (size_t)(s ? 2048 : 0) * DIM;
    u16* dst = (s ? Wmv : Wmq) + (size_t)b * DIM * DIM;

    const int t  = threadIdx.x;
    const int i0 = t * 4;
    float a[4][8];
    #pragma unroll
    for (int ii = 0; ii < 4; ++ii) {
        float4 a0 = reinterpret_cast<const float4*>(A + (size_t)(i0 + ii) * RANK)[0];
        float4 a1 = reinterpret_cast<const float4*>(A + (size_t)(i0 + ii) * RANK)[1];
        a[ii][0] = a0.x; a[ii][1] = a0.y; a[ii][2] = a0.z; a[ii][3] = a0.w;
        a[ii][4] = a1.x; a[ii][5] = a1.y; a[ii][6] = a1.z; a[ii][7] = a1.w;
    }
    for (int r = 0; r < 16; ++r) {
        const int o = og * 16 + r;
        float bv[8];
        #pragma unroll
        for (int rr = 0; rr < 8; ++rr) bv[rr] = Bp[(size_t)rr * DIM + o];
        f32x4 w = __builtin_nontemporal_load(
            reinterpret_cast<const f32x4*>(Ws + (size_t)o * DIM + i0));
        u16x4 ov;
        #pragma unroll
        for (int ii = 0; ii < 4; ++ii) {
            float d = 0.f;
            #pragma unroll
            for (int rr = 0; rr < 8; ++rr) d += a[ii][rr] * bv[rr];
            ov[ii] = f2bf(w[ii] + d);
        }
        *reinterpret_cast<u16x4*>(dst + (size_t)o * DIM + i0) = ov;
    }
}

// ---------------- 256x256 8-wave 8-phase GEMM (R9 pipeline; best measured) -------
// BK=64; LDS 2 buffers x (A 256x64 + B 256x64) = 128 KiB; 128B rows,
// swizzle: 16B group g of row r at slot g^(r&7) (measured 0-conflict),
// staged via pre-swizzled global source (rule #21).
// Fragment map (progressive halves): A m-frag f: rows wr*64+(f&3)*16+(f>>2)*128
// (f<4 -> A-half0); B n-frag n: rows wc*16+n*64 (n<2 -> B-half0).
// Stage order per tile: A0@ph0, B0@ph1, B1@ph2, A1@ph3 (of tile t+1).
// vmcnt ledger (2 loads/half; invariant {B1(t),A1(t)}=4 at tile start):
//   end ph0: vmcnt(4) retires B1(t); end ph1: vmcnt(4) retires A1(t);
//   end ph2: none; end ph3: vmcnt(4) retires A0,B0(t+1).
// Tail (tile 15): drain 4 -> 2 (ph0) -> 0 (ph1). All count-guaranteed.

__device__ __forceinline__ void stage_half(const u16* __restrict__ mat, int row0, int tk,
                                           u16* dst, int wave, int lane) {
    const int lrow = lane >> 3;
    const int g    = (lane & 7) ^ lrow;          // pre-swizzled 16B group
    const u16* gp = mat + (size_t)(row0 + wave * 8 + lrow) * DIM + tk + g * 8;
    u16* lp = dst + wave * 8 * 64;               // wave-uniform LDS base
    gl2lds16(gp, lp);
    gl2lds16(gp + (size_t)64 * DIM, lp + 64 * 64);
}

__device__ __forceinline__ void ds_read_A(const u16* sA, int wr, int lane,
                                          int kx0, int kx1, int mh, short8 (&a)[4][2]) {
    #pragma unroll
    for (int f = 0; f < 4; ++f) {
        const int row = wr * 64 + f * 16 + mh * 128 + (lane & 15);
        a[f][0] = *reinterpret_cast<const short8*>(sA + row * 64 + kx0);
        a[f][1] = *reinterpret_cast<const short8*>(sA + row * 64 + kx1);
    }
}
__device__ __forceinline__ void ds_read_B(const u16* sB, int wc, int lane,
                                          int kx0, int kx1, int nh, short8 (&b)[2][2]) {
    #pragma unroll
    for (int f = 0; f < 2; ++f) {
        const int row = wc * 16 + (nh * 2 + f) * 64 + (lane & 15);
        b[f][0] = *reinterpret_cast<const short8*>(sB + row * 64 + kx0);
        b[f][1] = *reinterpret_cast<const short8*>(sB + row * 64 + kx1);
    }
}

template <int MH, int NH>
__device__ __forceinline__ void mfma_quad(const short8 (&a)[4][2], const short8 (&b)[2][2],
                                          f32x4 (&acc)[8][4]) {
    #pragma unroll
    for (int ks = 0; ks < 2; ++ks)
        #pragma unroll
        for (int f = 0; f < 4; ++f)
            #pragma unroll
            for (int g = 0; g < 2; ++g)
                acc[MH * 4 + f][NH * 2 + g] = __builtin_amdgcn_mfma_f32_16x16x32_bf16(
                    a[f][ks], b[g][ks], acc[MH * 4 + f][NH * 2 + g], 0, 0, 0);
}

#define MFMA_BLOCK(MH, NH, AREG, BREG)                  \
    do {                                                \
        BAR();                                          \
        WAITL0();                                       \
        SCHED0();                                       \
        __builtin_amdgcn_s_setprio(1);                  \
        mfma_quad<MH, NH>(AREG, BREG, acc);             \
        __builtin_amdgcn_s_setprio(0);                  \
        SCHED0();                                       \
    } while (0)

__global__ __launch_bounds__(512, 2) void k_gemm(const u16* __restrict__ Xc,
                                                 const u16* __restrict__ Wk,
                                                 const u16* __restrict__ Wmq,
                                                 const u16* __restrict__ Wmv,
                                                 const float* __restrict__ bias,
                                                 float* __restrict__ out) {
    extern __shared__ u16 lds[];               // 128 KiB
    const int tid  = threadIdx.x;
    const int lane = tid & 63, wave = tid >> 6;
    const int wr = wave >> 2, wc = wave & 3;   // 2M x 4N wave grid

    // bijective XCD swizzle (nwg=1536, 1536%8==0)
    const int orig = blockIdx.x;
    const int wg   = (orig & 7) * 192 + (orig >> 3);
    const int bn   = wg % 12;
    const int bm   = wg / 12;
    const int m0 = bm * 256, n0 = bn * 256;
    const int batch = m0 >> 12;

    const u16* Bmat;
    int nc;
    if (n0 < DIM)           { Bmat = Wmq + (size_t)batch * DIM * DIM; nc = n0; }
    else if (n0 < 2 * DIM)  { Bmat = Wk;                              nc = n0 - DIM; }
    else                    { Bmat = Wmv + (size_t)batch * DIM * DIM; nc = n0 - 2 * DIM; }

    const int kx0 = (((lane >> 4)    ) ^ (lane & 7)) * 8;
    const int kx1 = (((lane >> 4) + 4) ^ (lane & 7)) * 8;

    f32x4 acc[8][4] = {};

    // prologue: tile 0 fully into buffer 0, drain once
    stage_half(Xc,   m0,       0, lds,                    wave, lane);
    stage_half(Bmat, nc,       0, lds + 16384,            wave, lane);
    stage_half(Bmat, nc + 128, 0, lds + 16384 + 128 * 64, wave, lane);
    stage_half(Xc,   m0 + 128, 0, lds + 128 * 64,         wave, lane);
    WAITV0(); BAR();

    #pragma unroll 1
    for (int t = 0; t < 15; ++t) {
        const u16* sA = lds + (t & 1) * 32768;
        const u16* sB = sA + 16384;
        u16* wA = lds + ((t + 1) & 1) * 32768;
        u16* wB = wA + 16384;
        const int tk1 = (t + 1) * 64;
        short8 a_lo[4][2], a_hi[4][2], b0[2][2], b1[2][2];

        // ---- phase 0: read Ah0(8)+Bh0(4); stage A0(t+1); quad(0,0) ----
        ds_read_A(sA, wr, lane, kx0, kx1, 0, a_lo);
        ds_read_B(sB, wc, lane, kx0, kx1, 0, b0);
        stage_half(Xc, m0, tk1, wA, wave, lane);
        WAITL8();
        MFMA_BLOCK(0, 0, a_lo, b0);
        WAITV4(); BAR();               // retire B1(t) (read next phase)

        // ---- phase 1: read Bh1(4); stage B0(t+1); quad(0,1) ----
        ds_read_B(sB, wc, lane, kx0, kx1, 1, b1);
        stage_half(Bmat, nc, tk1, wB, wave, lane);
        MFMA_BLOCK(0, 1, a_lo, b1);
        WAITV4(); BAR();               // retire A1(t) (read next phase)

        // ---- phase 2: read Ah1(8); stage B1(t+1); quad(1,0) ----
        ds_read_A(sA, wr, lane, kx0, kx1, 1, a_hi);
        stage_half(Bmat, nc + 128, tk1, wB + 128 * 64, wave, lane);
        MFMA_BLOCK(1, 0, a_hi, b0);
        BAR();

        // ---- phase 3: no reads; stage A1(t+1); quad(1,1); boundary ----
        stage_half(Xc, m0 + 128, tk1, wA + 128 * 64, wave, lane);
        MFMA_BLOCK(1, 1, a_hi, b1);
        WAITV4(); BAR();               // retire A0(t+1), B0(t+1) (read at ph0)
    }

    // ---- peeled tail: tile 15, no staging; count-guaranteed drain ----
    {
        const u16* sA = lds + 32768;   // 15 & 1 == 1
        const u16* sB = sA + 16384;
        short8 a_lo[4][2], a_hi[4][2], b0[2][2], b1[2][2];

        ds_read_A(sA, wr, lane, kx0, kx1, 0, a_lo);
        ds_read_B(sB, wc, lane, kx0, kx1, 0, b0);
        WAITL8();
        MFMA_BLOCK(0, 0, a_lo, b0);
        WAITV2(); BAR();               // retire B1(15) before its read

        ds_read_B(sB, wc, lane, kx0, kx1, 1, b1);
        MFMA_BLOCK(0, 1, a_lo, b1);
        WAITV0(); BAR();               // retire A1(15) before its read

        ds_read_A(sA, wr, lane, kx0, kx1, 1, a_hi);
        MFMA_BLOCK(1, 0, a_hi, b0);
        BAR();

        MFMA_BLOCK(1, 1, a_hi, b1);
    }

    // ---------------- epilogue: bias + store (plain; L2 write-combining) ----------
    const int cn = wc * 16 + (lane & 15);      // col within 256-block, + ni*64
    float bcol[4];
    #pragma unroll
    for (int ni = 0; ni < 4; ++ni) bcol[ni] = bias[n0 + cn + ni * 64];
    #pragma unroll
    for (int mi = 0; mi < 8; ++mi) {
        const int rb = m0 + wr * 64 + (mi & 3) * 16 + (mi >> 2) * 128 + (lane >> 4) * 4;
        #pragma unroll
        for (int v = 0; v < 4; ++v) {
            const size_t row = (size_t)(rb + v);
            #pragma unroll
            for (int ni = 0; ni < 4; ++ni)
                out[row * ODIM + (size_t)(n0 + cn + ni * 64)] = acc[mi][ni][v] + bcol[ni];
        }
    }
}

extern "C" void kernel_launch(void* const* d_in, const int* in_sizes, int n_in,
                              void* d_out, int out_size, void* d_ws, size_t ws_size,
                              hipStream_t stream) {
    const float* x      = (const float*)d_in[0];
    const float* weight = (const float*)d_in[1];
    const float* bias   = (const float*)d_in[2];
    const float* Aq     = (const float*)d_in[3];
    const float* Bq     = (const float*)d_in[4];
    const float* Av     = (const float*)d_in[5];
    const float* Bv     = (const float*)d_in[6];
    const int*   idx    = (const int*)d_in[7];
    float* out = (float*)d_out;

    // workspace: Xc(64MB) | Wk(2MB) | Wmq(16MB) | Wmv(16MB) = 98MB
    u16* Xc  = (u16*)d_ws;
    u16* Wk  = Xc + (size_t)MROWS * DIM;
    u16* Wmq = Wk + (size_t)DIM * DIM;
    u16* Wmv = Wmq + (size_t)8 * DIM * DIM;

    hipFuncSetAttribute(reinterpret_cast<const void*>(k_gemm),
                        hipFuncAttributeMaxDynamicSharedMemorySize, 131072);

    k_prep<<<3584, 256, 0, stream>>>(x, weight, Aq, Bq, Av, Bv, idx, Xc, Wk, Wmq, Wmv);
    k_gemm<<<1536, 512, 131072, stream>>>(Xc, Wk, Wmq, Wmv, bias, out);
}

// Round 19
// 264.894 us; speedup vs baseline: 1.4425x; 1.0492x over previous
//
#include <hip/hip_runtime.h>
#include <hip/hip_bf16.h>
#include <stdint.h>

#define DIM   1024
#define ODIM  3072
#define MROWS 32768   // B(8) * N(4096)
#define RANK  8

typedef unsigned short u16;
typedef __attribute__((ext_vector_type(8))) short short8;
typedef __attribute__((ext_vector_type(8))) unsigned short u16x8;
typedef __attribute__((ext_vector_type(4))) unsigned short u16x4;
typedef __attribute__((ext_vector_type(4))) float f32x4;

__device__ __forceinline__ u16 f2bf(float f) {
    uint32_t u = __float_as_uint(f);
    u += 0x7fffu + ((u >> 16) & 1u);   // RNE
    return (u16)(u >> 16);
}

__device__ __forceinline__ void gl2lds16(const void* g, void* l) {
    __builtin_amdgcn_global_load_lds(
        (const __attribute__((address_space(1))) void*)(uintptr_t)g,
        (__attribute__((address_space(3))) void*)(uint32_t)(uintptr_t)l,
        16, 0, 0);
}

#define BAR()    do { asm volatile("" ::: "memory"); __builtin_amdgcn_s_barrier(); asm volatile("" ::: "memory"); } while (0)
#define WAITV4() asm volatile("s_waitcnt vmcnt(4)" ::: "memory")
#define WAITV2() asm volatile("s_waitcnt vmcnt(2)" ::: "memory")
#define WAITV0() asm volatile("s_waitcnt vmcnt(0)" ::: "memory")
#define WAITL0() asm volatile("s_waitcnt lgkmcnt(0)" ::: "memory")
#define WAITL8() asm volatile("s_waitcnt lgkmcnt(8)" ::: "memory")
#define SCHED0() __builtin_amdgcn_sched_barrier(0)

// ---------------- fused prep: convert X | convert Wk | build Wmq/Wmv ----------------
__device__ __forceinline__ u16x8 cvt8_nt(const float* __restrict__ src) {
    f32x4 a = __builtin_nontemporal_load(reinterpret_cast<const f32x4*>(src));
    f32x4 b = __builtin_nontemporal_load(reinterpret_cast<const f32x4*>(src) + 1);
    u16x8 o;
    o[0] = f2bf(a[0]); o[1] = f2bf(a[1]); o[2] = f2bf(a[2]); o[3] = f2bf(a[3]);
    o[4] = f2bf(b[0]); o[5] = f2bf(b[1]); o[6] = f2bf(b[2]); o[7] = f2bf(b[3]);
    return o;
}

__global__ __launch_bounds__(256) void k_prep(const float* __restrict__ x,
                                              const float* __restrict__ W,
                                              const float* __restrict__ Aq_pool,
                                              const float* __restrict__ Bq_pool,
                                              const float* __restrict__ Av_pool,
                                              const float* __restrict__ Bv_pool,
                                              const int* __restrict__ idx,
                                              u16* __restrict__ Xc,
                                              u16* __restrict__ Wk,
                                              u16* __restrict__ Wmq,
                                              u16* __restrict__ Wmv) {
    if (blockIdx.x < 2048) {                       // ---- X convert ----
        const int stride = 2048 * 256;
        for (int t = blockIdx.x * 256 + threadIdx.x; t * 8 < MROWS * DIM; t += stride) {
            const int i = t * 8;
            *reinterpret_cast<u16x8*>(Xc + i) = cvt8_nt(x + i);
        }
        return;
    }
    if (blockIdx.x < 2560) {                       // ---- Wk convert ----
        const int i = ((blockIdx.x - 2048) * 256 + threadIdx.x) * 8;
        *reinterpret_cast<u16x8*>(Wk + i) = cvt8_nt(W + (size_t)DIM * DIM + i);
        return;
    }
    // ---- build ----
    const int bb = blockIdx.x - 2560;
    const int b  = bb >> 7;
    const int s  = (bb >> 6) & 1;
    const int og = bb & 63;
    const int p  = idx[b];
    const float* A  = (s ? Av_pool : Aq_pool) + (size_t)p * DIM * RANK;
    const float* Bp = (s ? Bv_pool : Bq_pool) + (size_t)p * RANK * DIM;
    const float* Ws = W + (size_t)(s ? 2048 : 0) * DIM;
    u16* dst = (s ? Wmv : Wmq) + (size_t)b * DIM * DIM;

    const int t  = threadIdx.x;
    const int i0 = t * 4;
    float a[4][8];
    #pragma unroll
    for (int ii = 0; ii < 4; ++ii) {
        float4 a0 = reinterpret_cast<const float4*>(A + (size_t)(i0 + ii) * RANK)[0];
        float4 a1 = reinterpret_cast<const float4*>(A + (size_t)(i0 + ii) * RANK)[1];
        a[ii][0] = a0.x; a[ii][1] = a0.y; a[ii][2] = a0.z; a[ii][3] = a0.w;
        a[ii][4] = a1.x; a[ii][5] = a1.y; a[ii][6] = a1.z; a[ii][7] = a1.w;
    }
    for (int r = 0; r < 16; ++r) {
        const int o = og * 16 + r;
        float bv[8];
        #pragma unroll
        for (int rr = 0; rr < 8; ++rr) bv[rr] = Bp[(size_t)rr * DIM + o];
        f32x4 w = __builtin_nontemporal_load(
            reinterpret_cast<const f32x4*>(Ws + (size_t)o * DIM + i0));
        u16x4 ov;
        #pragma unroll
        for (int ii = 0; ii < 4; ++ii) {
            float d = 0.f;
            #pragma unroll
            for (int rr = 0; rr < 8; ++rr) d += a[ii][rr] * bv[rr];
            ov[ii] = f2bf(w[ii] + d);
        }
        *reinterpret_cast<u16x4*>(dst + (size_t)o * DIM + i0) = ov;
    }
}

// ---------------- 256x256 8-wave 8-phase GEMM (R9 pipeline) ----------------
// K-loop identical to R17 (best measured). LDS-bounce epilogue with
// 1KB-contiguous f32x4 NONTEMPORAL stores — full HBM lines (avoids R14's
// +32% amplification) while keeping the 394MB output stream out of L2/LLC
// so X/W stay resident. R18 bug fixed: global store column is lane*4 (the
// de-swizzle happens on the LDS read; storing at (lane*4)^sw scrambled cols).

__device__ __forceinline__ void stage_half(const u16* __restrict__ mat, int row0, int tk,
                                           u16* dst, int wave, int lane) {
    const int lrow = lane >> 3;
    const int g    = (lane & 7) ^ lrow;          // pre-swizzled 16B group
    const u16* gp = mat + (size_t)(row0 + wave * 8 + lrow) * DIM + tk + g * 8;
    u16* lp = dst + wave * 8 * 64;               // wave-uniform LDS base
    gl2lds16(gp, lp);
    gl2lds16(gp + (size_t)64 * DIM, lp + 64 * 64);
}

__device__ __forceinline__ void ds_read_A(const u16* sA, int wr, int lane,
                                          int kx0, int kx1, int mh, short8 (&a)[4][2]) {
    #pragma unroll
    for (int f = 0; f < 4; ++f) {
        const int row = wr * 64 + f * 16 + mh * 128 + (lane & 15);
        a[f][0] = *reinterpret_cast<const short8*>(sA + row * 64 + kx0);
        a[f][1] = *reinterpret_cast<const short8*>(sA + row * 64 + kx1);
    }
}
__device__ __forceinline__ void ds_read_B(const u16* sB, int wc, int lane,
                                          int kx0, int kx1, int nh, short8 (&b)[2][2]) {
    #pragma unroll
    for (int f = 0; f < 2; ++f) {
        const int row = wc * 16 + (nh * 2 + f) * 64 + (lane & 15);
        b[f][0] = *reinterpret_cast<const short8*>(sB + row * 64 + kx0);
        b[f][1] = *reinterpret_cast<const short8*>(sB + row * 64 + kx1);
    }
}

template <int MH, int NH>
__device__ __forceinline__ void mfma_quad(const short8 (&a)[4][2], const short8 (&b)[2][2],
                                          f32x4 (&acc)[8][4]) {
    #pragma unroll
    for (int ks = 0; ks < 2; ++ks)
        #pragma unroll
        for (int f = 0; f < 4; ++f)
            #pragma unroll
            for (int g = 0; g < 2; ++g)
                acc[MH * 4 + f][NH * 2 + g] = __builtin_amdgcn_mfma_f32_16x16x32_bf16(
                    a[f][ks], b[g][ks], acc[MH * 4 + f][NH * 2 + g], 0, 0, 0);
}

#define MFMA_BLOCK(MH, NH, AREG, BREG)                  \
    do {                                                \
        BAR();                                          \
        WAITL0();                                       \
        SCHED0();                                       \
        __builtin_amdgcn_s_setprio(1);                  \
        mfma_quad<MH, NH>(AREG, BREG, acc);             \
        __builtin_amdgcn_s_setprio(0);                  \
        SCHED0();                                       \
    } while (0)

__global__ __launch_bounds__(512, 2) void k_gemm(const u16* __restrict__ Xc,
                                                 const u16* __restrict__ Wk,
                                                 const u16* __restrict__ Wmq,
                                                 const u16* __restrict__ Wmv,
                                                 const float* __restrict__ bias,
                                                 float* __restrict__ out) {
    extern __shared__ u16 lds[];               // 128 KiB
    const int tid  = threadIdx.x;
    const int lane = tid & 63, wave = tid >> 6;
    const int wr = wave >> 2, wc = wave & 3;   // 2M x 4N wave grid

    // bijective XCD swizzle (nwg=1536, 1536%8==0)
    const int orig = blockIdx.x;
    const int wg   = (orig & 7) * 192 + (orig >> 3);
    const int bn   = wg % 12;
    const int bm   = wg / 12;
    const int m0 = bm * 256, n0 = bn * 256;
    const int batch = m0 >> 12;

    const u16* Bmat;
    int nc;
    if (n0 < DIM)           { Bmat = Wmq + (size_t)batch * DIM * DIM; nc = n0; }
    else if (n0 < 2 * DIM)  { Bmat = Wk;                              nc = n0 - DIM; }
    else                    { Bmat = Wmv + (size_t)batch * DIM * DIM; nc = n0 - 2 * DIM; }

    const int kx0 = (((lane >> 4)    ) ^ (lane & 7)) * 8;
    const int kx1 = (((lane >> 4) + 4) ^ (lane & 7)) * 8;

    f32x4 acc[8][4] = {};

    // prologue: tile 0 fully into buffer 0, drain once
    stage_half(Xc,   m0,       0, lds,                    wave, lane);
    stage_half(Bmat, nc,       0, lds + 16384,            wave, lane);
    stage_half(Bmat, nc + 128, 0, lds + 16384 + 128 * 64, wave, lane);
    stage_half(Xc,   m0 + 128, 0, lds + 128 * 64,         wave, lane);
    WAITV0(); BAR();

    #pragma unroll 1
    for (int t = 0; t < 15; ++t) {
        const u16* sA = lds + (t & 1) * 32768;
        const u16* sB = sA + 16384;
        u16* wA = lds + ((t + 1) & 1) * 32768;
        u16* wB = wA + 16384;
        const int tk1 = (t + 1) * 64;
        short8 a_lo[4][2], a_hi[4][2], b0[2][2], b1[2][2];

        // ---- phase 0: read Ah0(8)+Bh0(4); stage A0(t+1); quad(0,0) ----
        ds_read_A(sA, wr, lane, kx0, kx1, 0, a_lo);
        ds_read_B(sB, wc, lane, kx0, kx1, 0, b0);
        stage_half(Xc, m0, tk1, wA, wave, lane);
        WAITL8();
        MFMA_BLOCK(0, 0, a_lo, b0);
        WAITV4(); BAR();               // retire B1(t) (read next phase)

        // ---- phase 1: read Bh1(4); stage B0(t+1); quad(0,1) ----
        ds_read_B(sB, wc, lane, kx0, kx1, 1, b1);
        stage_half(Bmat, nc, tk1, wB, wave, lane);
        MFMA_BLOCK(0, 1, a_lo, b1);
        WAITV4(); BAR();               // retire A1(t) (read next phase)

        // ---- phase 2: read Ah1(8); stage B1(t+1); quad(1,0) ----
        ds_read_A(sA, wr, lane, kx0, kx1, 1, a_hi);
        stage_half(Bmat, nc + 128, tk1, wB + 128 * 64, wave, lane);
        MFMA_BLOCK(1, 0, a_hi, b0);
        BAR();

        // ---- phase 3: no reads; stage A1(t+1); quad(1,1); boundary ----
        stage_half(Xc, m0 + 128, tk1, wA + 128 * 64, wave, lane);
        MFMA_BLOCK(1, 1, a_hi, b1);
        WAITV4(); BAR();               // retire A0(t+1), B0(t+1) (read at ph0)
    }

    // ---- peeled tail: tile 15, no staging; count-guaranteed drain ----
    {
        const u16* sA = lds + 32768;   // 15 & 1 == 1
        const u16* sB = sA + 16384;
        short8 a_lo[4][2], a_hi[4][2], b0[2][2], b1[2][2];

        ds_read_A(sA, wr, lane, kx0, kx1, 0, a_lo);
        ds_read_B(sB, wc, lane, kx0, kx1, 0, b0);
        WAITL8();
        MFMA_BLOCK(0, 0, a_lo, b0);
        WAITV2(); BAR();               // retire B1(15) before its read

        ds_read_B(sB, wc, lane, kx0, kx1, 1, b1);
        MFMA_BLOCK(0, 1, a_lo, b1);
        WAITV0(); BAR();               // retire A1(15) before its read

        ds_read_A(sA, wr, lane, kx0, kx1, 1, a_hi);
        MFMA_BLOCK(1, 0, a_hi, b0);
        BAR();

        MFMA_BLOCK(1, 1, a_hi, b1);
    }

    // ---------------- epilogue: LDS-bounce + full-line nontemporal stores ----------
    // Slab s (16 rows x 256 cols f32, 16KB) holds global rows m0+r*128+s*16.
    // Write: wave (wr,wc) deposits quadrant q of round r into slab wr*4+q at
    // columns wc*16+(lane&15)+ni*64, XOR-swizzled (col ^ ((row&7)<<2)).
    // Read: position p holds column p^sw; base (lane*4)^sw is 4-aligned and sw
    // has no low-2 bits, so the f32x4 at that base = columns lane*4..lane*4+3.
    // Store to global at column lane*4 (UNSWIZZLED — R18's bug was ^sw here):
    // 64 lanes x 16B = 1KB contiguous NT store -> full HBM lines, no LLC fill.
    {
        float* fl = reinterpret_cast<float*>(lds);   // 32768 floats
        const int cn = wc * 16 + (lane & 15);
        float bcol[4];
        #pragma unroll
        for (int ni = 0; ni < 4; ++ni) bcol[ni] = bias[n0 + cn + ni * 64];

        BAR();                          // all LDS reads of tile 15 complete
        #pragma unroll
        for (int r = 0; r < 2; ++r) {
            #pragma unroll
            for (int q = 0; q < 4; ++q) {
                const int mi   = r * 4 + q;
                const int slab = wr * 4 + q;
                #pragma unroll
                for (int v = 0; v < 4; ++v) {
                    const int row = (lane >> 4) * 4 + v;          // 0..15
                    const int sw  = (row & 7) << 2;
                    #pragma unroll
                    for (int ni = 0; ni < 4; ++ni) {
                        const int col = cn + ni * 64;
                        fl[slab * 4096 + row * 256 + (col ^ sw)] =
                            acc[mi][ni][v] + bcol[ni];
                    }
                }
            }
            BAR();
            {
                const int slab  = wave;
                const int grow0 = m0 + r * 128 + slab * 16;
                #pragma unroll
                for (int row = 0; row < 16; ++row) {
                    const int sw = (row & 7) << 2;
                    f32x4 vv = *reinterpret_cast<const f32x4*>(
                        &fl[slab * 4096 + row * 256 + ((lane * 4) ^ sw)]);
                    __builtin_nontemporal_store(vv,
                        reinterpret_cast<f32x4*>(
                            &out[(size_t)(grow0 + row) * ODIM + n0 + lane * 4]));
                }
            }
            BAR();
        }
    }
}

extern "C" void kernel_launch(void* const* d_in, const int* in_sizes, int n_in,
                              void* d_out, int out_size, void* d_ws, size_t ws_size,
                              hipStream_t stream) {
    const float* x      = (const float*)d_in[0];
    const float* weight = (const float*)d_in[1];
    const float* bias   = (const float*)d_in[2];
    const float* Aq     = (const float*)d_in[3];
    const float* Bq     = (const float*)d_in[4];
    const float* Av     = (const float*)d_in[5];
    const float* Bv     = (const float*)d_in[6];
    const int*   idx    = (const int*)d_in[7];
    float* out = (float*)d_out;

    // workspace: Xc(64MB) | Wk(2MB) | Wmq(16MB) | Wmv(16MB) = 98MB
    u16* Xc  = (u16*)d_ws;
    u16* Wk  = Xc + (size_t)MROWS * DIM;
    u16* Wmq = Wk + (size_t)DIM * DIM;
    u16* Wmv = Wmq + (size_t)8 * DIM * DIM;

    hipFuncSetAttribute(reinterpret_cast<const void*>(k_gemm),
                        hipFuncAttributeMaxDynamicSharedMemorySize, 131072);

    k_prep<<<3584, 256, 0, stream>>>(x, weight, Aq, Bq, Av, Bv, idx, Xc, Wk, Wmq, Wmv);
    k_gemm<<<1536, 512, 131072, stream>>>(Xc, Wk, Wmq, Wmv, bias, out);
}